// Round 1
// baseline (255.313 us; speedup 1.0000x reference)
//
#include <hip/hip_runtime.h>

#define M1 81
#define MSZ 80
#define NEL (M1 * M1)          // 6561
#define NTW ((NEL + 31) / 32)  // 206 words of target bits
#define NACC 12
#define PSTR 16                // padded per-block partial stride (floats)

// accumulator indices:
// 0 target_num, 1 n_pre, 2 n_next, 3 n_union,
// 4 s_pre, 5 s_next, 6 s_all, 7 s_sim,
// 8 s_acc_pre, 9 s_acc_next, 10 n_mpre, 11 n_mnext

__global__ __launch_bounds__(256) void sst_main(
    const float* __restrict__ input,
    const int* __restrict__ target,
    const int* __restrict__ mask0,
    const int* __restrict__ mask1,
    float* __restrict__ out_idx,   // d_out + 7, [slices*80] floats
    float* __restrict__ part)      // [slices * PSTR] block partials
{
    __shared__ float s_x[NEL];
    __shared__ unsigned int s_tb[NTW];
    __shared__ float s_m0[M1], s_m1[M1];
    __shared__ float s_rmax[M1], s_rsum[M1];
    __shared__ float s_cmax[M1], s_csum[M1];
    __shared__ float s_accf[NACC];

    const int tid = threadIdx.x;
    const int slice = blockIdx.x;
    const size_t base = (size_t)slice * NEL;

    if (tid < NACC) s_accf[tid] = 0.0f;
    if (tid >= 32 && tid < 32 + M1)  s_m0[tid - 32]  = (float)mask0[slice * M1 + (tid - 32)];
    if (tid >= 128 && tid < 128 + M1) s_m1[tid - 128] = (float)mask1[slice * M1 + (tid - 128)];

    // stage input tile + pack target bits (ballot: 64 consecutive flat elems per wave)
    for (int i = tid; i < NEL; i += 256) {
        s_x[i] = input[base + i];
        bool t = (target[base + i] != 0);
        unsigned long long m = __ballot(t);
        if ((tid & 63) == 0) {
            int w = (i & ~63) >> 5;
            s_tb[w] = (unsigned int)m;
            if (w + 1 < NTW) s_tb[w + 1] = (unsigned int)(m >> 32);
        }
    }
    __syncthreads();

    // ---- phase 1: softmax stats. rows on tid<81, cols on tid in [128,209) ----
    if (tid < M1) {
        const int r = tid;
        const float m0r = s_m0[r];
        const bool lastrow = (r == MSZ);
        float rmax = -3.402823466e38f;
        for (int c = 0; c < M1; ++c) {
            float mp = lastrow ? 0.0f : m0r * s_m1[c];
            float xv = mp * s_x[r * M1 + c];
            rmax = fmaxf(rmax, xv);
        }
        float rsum = 0.0f;
        for (int c = 0; c < M1; ++c) {
            float mp = lastrow ? 0.0f : m0r * s_m1[c];
            float xv = mp * s_x[r * M1 + c];
            rsum += expf(xv - rmax);
        }
        s_rmax[r] = rmax;
        s_rsum[r] = rsum;
    } else if (tid >= 128 && tid < 128 + M1) {
        const int c = tid - 128;
        const float m1c = s_m1[c];
        const bool lastcol = (c == MSZ);
        float cmax = -3.402823466e38f;
        for (int r = 0; r < M1; ++r) {
            float mn = lastcol ? 0.0f : s_m0[r] * m1c;
            float xv = mn * s_x[r * M1 + c];
            cmax = fmaxf(cmax, xv);
        }
        float csum = 0.0f;
        for (int r = 0; r < M1; ++r) {
            float mn = lastcol ? 0.0f : s_m0[r] * m1c;
            float xv = mn * s_x[r * M1 + c];
            csum += expf(xv - cmax);
        }
        s_cmax[c] = cmax;
        s_csum[c] = csum;
    }
    __syncthreads();

    // ---- phase 2: accumulation ----
    float a[NACC];
#pragma unroll
    for (int k = 0; k < NACC; ++k) a[k] = 0.0f;

    if (tid < M1) {
        const int r = tid;
        const float m0r = s_m0[r];
        const bool lastrow = (r == MSZ);
        const float rmax = s_rmax[r];
        const float rsum = s_rsum[r];
        float best = -1.0f; int bidx = 0;
        int tIdx = 0; bool tFound = false;
        for (int c = 0; c < M1; ++c) {
            const int idx = r * M1 + c;
            const float x = s_x[idx];
            const float m1c = s_m1[c];
            const float mreg = m0r * m1c;
            const float mpre = lastrow ? 0.0f : mreg;
            const float mnext = (c == MSZ) ? 0.0f : mreg;
            const float t = (float)((s_tb[idx >> 5] >> (idx & 31)) & 1u);
            a[0] += t;  // target_num over ALL elements
            const float p_pre = expf(mpre * x - rmax) / rsum;
            const float p_next = expf(mnext * x - s_cmax[c]) / s_csum[c];
            const float tpre = t * mpre;
            a[1] += tpre;
            if (!tFound && tpre != 0.0f) { tIdx = c; tFound = true; }
            a[4] -= tpre * logf(p_pre);
            const float pall = (!lastrow && c < MSZ) ? fmaxf(p_pre, p_next) : p_pre;
            a[6] -= tpre * logf(pall);
            const float mun = (lastrow || c == MSZ) ? 0.0f : mreg;
            const float tun = t * mun;
            a[3] += tun;
            a[7] += tun * fabsf(p_next - p_pre);
            if (pall > best) { best = pall; bidx = c; }  // first-max argmax
        }
        if (!lastrow) {
            out_idx[(size_t)slice * MSZ + r] = (float)bidx;
            a[8] += (bidx == tIdx) ? m0r : 0.0f;
            a[10] += m0r;
        }
    } else if (tid >= 128 && tid < 128 + M1) {
        const int c = tid - 128;
        const float m1c = s_m1[c];
        const bool lastcol = (c == MSZ);
        const float cmax = s_cmax[c];
        const float csum = s_csum[c];
        float best = -1.0f; int bidx = 0;
        int tIdx = 0; bool tFound = false;
        for (int r = 0; r < M1; ++r) {
            const int idx = r * M1 + c;
            const float x = s_x[idx];
            const float mreg = s_m0[r] * m1c;
            const float mnext = lastcol ? 0.0f : mreg;
            const float t = (float)((s_tb[idx >> 5] >> (idx & 31)) & 1u);
            const float p_next = expf(mnext * x - cmax) / csum;
            const float tnext = t * mnext;
            a[2] += tnext;
            a[5] -= tnext * logf(p_next);
            if (!tFound && tnext != 0.0f) { tIdx = r; tFound = true; }
            if (p_next > best) { best = p_next; bidx = r; }  // first-max argmax over rows
        }
        if (!lastcol) {
            a[9] += (bidx == tIdx) ? m1c : 0.0f;
            a[11] += m1c;
        }
    }

    // ---- block reduce: wave shuffle -> LDS float atomic -> per-block partial row ----
#pragma unroll
    for (int k = 0; k < NACC; ++k) {
        float v = a[k];
        for (int off = 32; off > 0; off >>= 1) v += __shfl_down(v, off);
        if ((tid & 63) == 0) atomicAdd(&s_accf[k], v);
    }
    __syncthreads();
    if (tid < NACC) part[(size_t)slice * PSTR + tid] = s_accf[tid];
}

__global__ __launch_bounds__(256) void sst_final(
    const float* __restrict__ part, int slices, float* __restrict__ out)
{
    __shared__ double s_part[4][NACC];
    const int tid = threadIdx.x;
    double l[NACC];
#pragma unroll
    for (int k = 0; k < NACC; ++k) l[k] = 0.0;
    for (int s = tid; s < slices; s += 256) {
#pragma unroll
        for (int k = 0; k < NACC; ++k) l[k] += (double)part[(size_t)s * PSTR + k];
    }
#pragma unroll
    for (int k = 0; k < NACC; ++k) {
        double v = l[k];
        for (int off = 32; off > 0; off >>= 1) v += __shfl_down(v, off);
        if ((tid & 63) == 0) s_part[tid >> 6][k] = v;
    }
    __syncthreads();
    if (tid == 0) {
        double g[NACC];
#pragma unroll
        for (int k = 0; k < NACC; ++k)
            g[k] = s_part[0][k] + s_part[1][k] + s_part[2][k] + s_part[3][k];
        const double tnum = g[0], npre = g[1], nnext = g[2], nunion = g[3];
        const double spre = g[4], snext = g[5], sall = g[6], ssim = g[7];
        const double accp = g[8], accn = g[9], nmp = g[10], nmn = g[11];
        const double loss_pre  = (npre > 0.0) ? spre / npre : spre;
        const double loss_next = (nnext > 0.0) ? snext / nnext : snext;
        const double loss      = (npre > 0.0 && nnext > 0.0) ? sall / npre : sall;
        const double loss_sim  = (nunion > 0.0) ? ssim / tnum : ssim;
        const double total = (loss_pre + loss_next + loss + loss_sim) * 0.25;
        const double ap = (nmp > 0.0) ? accp / nmp : accp + 1.0;
        const double an = (nmn > 0.0) ? accn / nmn : accn + 1.0;
        out[0] = (float)loss_pre;
        out[1] = (float)loss_next;
        out[2] = (float)loss_sim;
        out[3] = (float)total;
        out[4] = (float)ap;
        out[5] = (float)an;
        out[6] = (float)((ap + an) * 0.5);
    }
}

extern "C" void kernel_launch(void* const* d_in, const int* in_sizes, int n_in,
                              void* d_out, int out_size, void* d_ws, size_t ws_size,
                              hipStream_t stream) {
    const float* input  = (const float*)d_in[0];
    const int*   target = (const int*)d_in[1];
    const int*   mask0  = (const int*)d_in[2];
    const int*   mask1  = (const int*)d_in[3];
    float* out = (float*)d_out;
    float* part = (float*)d_ws;   // slices * PSTR floats

    const int slices = in_sizes[0] / NEL;  // B*C = 2048

    sst_main<<<slices, 256, 0, stream>>>(input, target, mask0, mask1, out + 7, part);
    sst_final<<<1, 256, 0, stream>>>(part, slices, out);
}

// Round 2
// 190.866 us; speedup vs baseline: 1.3377x; 1.3377x over previous
//
#include <hip/hip_runtime.h>

#define M1 81
#define MSZ 80
#define NEL (M1 * M1)          // 6561
#define NTW ((NEL + 31) / 32)  // 206 words of target bits
#define NACC 12
#define PSTR 16                // padded per-block partial stride (floats)

// accumulator indices:
// 0 target_num, 1 n_pre, 2 n_next, 3 n_union,
// 4 s_pre, 5 s_next, 6 s_all, 7 s_sim,
// 8 s_acc_pre, 9 s_acc_next, 10 n_mpre, 11 n_mnext

__device__ __forceinline__ float tbit(const unsigned* tb, int idx) {
    return (float)((tb[idx >> 5] >> (idx & 31)) & 1u);
}

__global__ __launch_bounds__(256) void sst_main(
    const float* __restrict__ input,
    const int* __restrict__ target,
    const int* __restrict__ mask0,
    const int* __restrict__ mask1,
    float* __restrict__ out_idx,   // d_out + 7, [slices*80] floats
    float* __restrict__ part)      // [slices * PSTR] block partials
{
    __shared__ float s_x[NEL];
    __shared__ unsigned s_tb[NTW];
    __shared__ float s_m0[M1], s_m1[M1];
    __shared__ float s_lr[M1];     // log(rsum) per row
    __shared__ float s_kc[M1];     // log(csum) per col
    __shared__ int   s_tidx[M1];   // first target col per row (argmax target_pre)
    __shared__ float s_bl[MSZ];    // half1 best log-prob per row
    __shared__ int   s_bi[MSZ];    // half1 best col per row
    __shared__ float s_accf[NACC];

    const int tid = threadIdx.x;
    const int slice = blockIdx.x;
    const size_t base = (size_t)slice * NEL;

    if (tid < NACC) s_accf[tid] = 0.0f;
    if (tid >= 32 && tid < 32 + M1)  s_m0[tid - 32]  = (float)mask0[slice * M1 + (tid - 32)];
    if (tid >= 128 && tid < 128 + M1) s_m1[tid - 128] = (float)mask1[slice * M1 + (tid - 128)];

    // stage input tile + pack target bits (ballot: 64 consecutive flat elems per wave)
    for (int i = tid; i < NEL; i += 256) {
        s_x[i] = input[base + i];
        bool t = (target[base + i] != 0);
        unsigned long long m = __ballot(t);
        if ((tid & 63) == 0) {
            int w = (i & ~63) >> 5;
            s_tb[w] = (unsigned)m;
            if (w + 1 < NTW) s_tb[w + 1] = (unsigned)(m >> 32);
        }
    }
    __syncthreads();

    float a[NACC];
#pragma unroll
    for (int k = 0; k < NACC; ++k) a[k] = 0.0f;

    // ---- phase A: softmax sums (no max subtraction: |x|<~6, exp safe) +
    //      linear CE stats. rows on tid<81, cols on tid in [128,209). ----
    if (tid < M1) {
        const int r = tid;
        const float m0r = s_m0[r];
        const float mrow = (r == MSZ) ? 0.0f : m0r;  // mpre = mrow * m1c
        const int rowbase = r * M1;
        float rsum = 0.0f, S_t = 0.0f, S_tx = 0.0f, a0 = 0.0f;
        int tIdx = 0; bool found = false;
        for (int c = 0; c < M1; ++c) {
            const float x = s_x[rowbase + c];
            const float mpre = mrow * s_m1[c];
            const float xv = mpre * x;
            rsum += __expf(xv);
            const float tf = tbit(s_tb, rowbase + c);
            a0 += tf;
            const float tpre = tf * mpre;
            S_t += tpre;
            S_tx = fmaf(tpre, xv, S_tx);
            if (!found && tpre != 0.0f) { tIdx = c; found = true; }
        }
        const float lr = __logf(rsum);
        s_lr[r] = lr;
        s_tidx[r] = tIdx;
        a[0] += a0;
        a[1] += S_t;
        a[4] += S_t * lr - S_tx;   // -sum tpre*log(p_pre) = S_t*log(rsum) - sum tpre*xv
    } else if (tid >= 128 && tid < 128 + M1) {
        const int c = tid - 128;
        const float m1c = s_m1[c];
        const float mcol = (c == MSZ) ? 0.0f : m1c;  // mnext = mcol * m0r
        float csum = 0.0f, S_tn = 0.0f, S_tnx = 0.0f;
        float best = -1.0f; int bidx = 0;
        int tIdxn = 0; bool found = false;
        for (int r = 0; r < M1; ++r) {
            const float x = s_x[r * M1 + c];
            const float mnext = mcol * s_m0[r];
            const float xn = mnext * x;
            const float e = __expf(xn);
            csum += e;
            if (e > best) { best = e; bidx = r; }  // first-max (same order as p_next)
            const float tf = tbit(s_tb, r * M1 + c);
            const float tnext = tf * mnext;
            S_tn += tnext;
            S_tnx = fmaf(tnext, xn, S_tnx);
            if (!found && tnext != 0.0f) { tIdxn = r; found = true; }
        }
        const float lc = __logf(csum);
        s_kc[c] = lc;
        a[2] += S_tn;
        a[5] += S_tn * lc - S_tnx;
        if (c < MSZ) {
            a[9] += (bidx == tIdxn) ? m1c : 0.0f;
            a[11] += m1c;
        }
    }
    __syncthreads();

    // ---- phase B: per-element log-prob work, rows split 2 threads/row.
    //      half0 = tid 0..79 (cols 0..40), half1 = tid 128..207 (cols 41..80)
    //      -> each wave holds a single half, so c (and the m1c guard) stays
    //         wave-uniform. ----
    const bool bh0 = (tid < MSZ);
    const bool bh1 = (tid >= 128 && tid < 128 + MSZ);
    float bbest = -3.402823466e38f;
    int bbidx = 0;
    if (bh0 || bh1) {
        const int r = bh0 ? tid : (tid - 128);
        const int rowbase = r * M1;
        const float m0r = s_m0[r];
        const float lr = s_lr[r];
        const int c0 = bh1 ? 41 : 0;
        const int c1 = bh1 ? MSZ : 41;
        bbidx = c0;
        for (int c = c0; c < c1; ++c) {
            const float m1c = s_m1[c];
            const float x = s_x[rowbase + c];
            const float mp = m0r * m1c;            // == mpre == mnext here (r<80,c<80)
            const float lp_pre  = fmaf(mp, x, -lr);
            const float lp_next = fmaf(mp, x, -s_kc[c]);
            const float lpall = fmaxf(lp_pre, lp_next);
            if (lpall > bbest) { bbest = lpall; bbidx = c; }
            const float tf = tbit(s_tb, rowbase + c);
            const float tpre = tf * mp;            // == tun here
            a[6] = fmaf(-tpre, lpall, a[6]);
            a[3] += tpre;
            if (m1c != 0.0f) {                     // wave-uniform skip
                const float ppre  = __expf(lp_pre);
                const float pnext = __expf(lp_next);
                a[7] = fmaf(tpre, fabsf(pnext - ppre), a[7]);
            }
        }
        if (bh1) {  // c = 80 column: input_all = input_pre there; no union/sim
            const float m1c = s_m1[MSZ];
            const float x = s_x[rowbase + MSZ];
            const float mp = m0r * m1c;
            const float lp = fmaf(mp, x, -lr);
            if (lp > bbest) { bbest = lp; bbidx = MSZ; }
            const float tpre = tbit(s_tb, rowbase + MSZ) * mp;
            a[6] = fmaf(-tpre, lp, a[6]);
            s_bl[r] = bbest;
            s_bi[r] = bbidx;
        }
    }
    __syncthreads();

    if (tid < MSZ) {  // half0 merges argmax (>= favors lower-c half: first-max)
        const int r = tid;
        const float b1 = s_bl[r];
        const int gb = (bbest >= b1) ? bbidx : s_bi[r];
        out_idx[(size_t)slice * MSZ + r] = (float)gb;
        const float m0r = s_m0[r];
        a[8] += (gb == s_tidx[r]) ? m0r : 0.0f;
        a[10] += m0r;
    }

    // ---- block reduce: wave shuffle -> LDS float atomic -> per-block partial row ----
#pragma unroll
    for (int k = 0; k < NACC; ++k) {
        float v = a[k];
        for (int off = 32; off > 0; off >>= 1) v += __shfl_down(v, off);
        if ((tid & 63) == 0) atomicAdd(&s_accf[k], v);
    }
    __syncthreads();
    if (tid < NACC) part[(size_t)slice * PSTR + tid] = s_accf[tid];
}

__global__ __launch_bounds__(256) void sst_final(
    const float* __restrict__ part, int slices, float* __restrict__ out)
{
    __shared__ double s_part[4][NACC];
    const int tid = threadIdx.x;
    double l[NACC];
#pragma unroll
    for (int k = 0; k < NACC; ++k) l[k] = 0.0;
    for (int s = tid; s < slices; s += 256) {
#pragma unroll
        for (int k = 0; k < NACC; ++k) l[k] += (double)part[(size_t)s * PSTR + k];
    }
#pragma unroll
    for (int k = 0; k < NACC; ++k) {
        double v = l[k];
        for (int off = 32; off > 0; off >>= 1) v += __shfl_down(v, off);
        if ((tid & 63) == 0) s_part[tid >> 6][k] = v;
    }
    __syncthreads();
    if (tid == 0) {
        double g[NACC];
#pragma unroll
        for (int k = 0; k < NACC; ++k)
            g[k] = s_part[0][k] + s_part[1][k] + s_part[2][k] + s_part[3][k];
        const double tnum = g[0], npre = g[1], nnext = g[2], nunion = g[3];
        const double spre = g[4], snext = g[5], sall = g[6], ssim = g[7];
        const double accp = g[8], accn = g[9], nmp = g[10], nmn = g[11];
        const double loss_pre  = (npre > 0.0) ? spre / npre : spre;
        const double loss_next = (nnext > 0.0) ? snext / nnext : snext;
        const double loss      = (npre > 0.0 && nnext > 0.0) ? sall / npre : sall;
        const double loss_sim  = (nunion > 0.0) ? ssim / tnum : ssim;
        const double total = (loss_pre + loss_next + loss + loss_sim) * 0.25;
        const double ap = (nmp > 0.0) ? accp / nmp : accp + 1.0;
        const double an = (nmn > 0.0) ? accn / nmn : accn + 1.0;
        out[0] = (float)loss_pre;
        out[1] = (float)loss_next;
        out[2] = (float)loss_sim;
        out[3] = (float)total;
        out[4] = (float)ap;
        out[5] = (float)an;
        out[6] = (float)((ap + an) * 0.5);
    }
}

extern "C" void kernel_launch(void* const* d_in, const int* in_sizes, int n_in,
                              void* d_out, int out_size, void* d_ws, size_t ws_size,
                              hipStream_t stream) {
    const float* input  = (const float*)d_in[0];
    const int*   target = (const int*)d_in[1];
    const int*   mask0  = (const int*)d_in[2];
    const int*   mask1  = (const int*)d_in[3];
    float* out = (float*)d_out;
    float* part = (float*)d_ws;   // slices * PSTR floats

    const int slices = in_sizes[0] / NEL;  // B*C = 2048

    sst_main<<<slices, 256, 0, stream>>>(input, target, mask0, mask1, out + 7, part);
    sst_final<<<1, 256, 0, stream>>>(part, slices, out);
}

// Round 3
// 183.283 us; speedup vs baseline: 1.3930x; 1.0414x over previous
//
#include <hip/hip_runtime.h>

#define M1 81
#define MSZ 80
#define NEL (M1 * M1)          // 6561
#define NTW ((NEL + 31) / 32)  // 206 words of target bits
#define NACC 12

// accumulator indices:
// 0 target_num, 1 n_pre, 2 n_next, 3 n_union,
// 4 s_pre, 5 s_next, 6 s_all, 7 s_sim,
// 8 s_acc_pre, 9 s_acc_next, 10 n_mpre, 11 n_mnext

__device__ __forceinline__ float tbitf(const unsigned* tb, int idx) {
    return (float)((tb[idx >> 5] >> (idx & 31)) & 1u);
}

__global__ __launch_bounds__(256) void sst_main(
    const float* __restrict__ input,
    const int* __restrict__ target,
    const int* __restrict__ mask0,
    const int* __restrict__ mask1,
    float* __restrict__ out_idx,   // d_out + 7, [slices*80] floats
    float* __restrict__ part,      // SoA: part[k*slices + slice]
    int slices)
{
    __shared__ float s_x[NEL];
    __shared__ unsigned s_tb[NTW];
    __shared__ float s_m0[M1], s_m1[M1];
    __shared__ float2 s_rowc[M1];      // {lr = log(rsum), 1/rsum}
    __shared__ float4 s_colc[M1];      // {m1c, kc = log(csum), 1/csum, 0}
    __shared__ float s_pa[243];        // partial sums scratch
    __shared__ float s_pv[243];        // partial argmax value
    __shared__ unsigned char s_pi[243];// partial argmax index
    __shared__ unsigned char s_pt[243];// partial first-target index (127 = none)
    __shared__ float s_accf[NACC];

    const int tid = threadIdx.x;
    const int slice = blockIdx.x;
    const size_t base = (size_t)slice * NEL;

    if (tid < NACC) s_accf[tid] = 0.0f;
    if (tid < M1) s_m0[tid] = (float)mask0[slice * M1 + tid];
    else if (tid >= 128 && tid < 128 + M1) s_m1[tid - 128] = (float)mask1[slice * M1 + (tid - 128)];

    // stage input tile + pack target bits (ballot packs 64 consecutive elems)
    for (int i = tid; i < NEL; i += 256) {
        s_x[i] = input[base + i];
        unsigned long long m = __ballot(target[base + i] != 0);
        if ((tid & 63) == 0) {
            int w = (i >> 5) & ~1;      // (i & ~63) >> 5
            s_tb[w] = (unsigned)m;
            if (w + 1 < NTW) s_tb[w + 1] = (unsigned)(m >> 32);
        }
    }
    __syncthreads();

    float a[NACC];
#pragma unroll
    for (int k = 0; k < NACC; ++k) a[k] = 0.0f;

    const int g  = tid / 3;        // row (or col) id for 3-thread teams
    const int j  = tid - 3 * g;    // chunk 0..2
    const int c0 = j * 27;
    const bool act = (tid < 243);

    // ---- pass 1a: row softmax denominators (includes col 80; row 80 masked) ----
    if (act) {
        const int r = g;
        const float m0p = (r == MSZ) ? 0.0f : s_m0[r];
        const int rb = r * M1;
        float rs = 0.0f;
        for (int i = 0; i < 27; ++i) {
            const int c = c0 + i;
            rs += __expf(m0p * s_m1[c] * s_x[rb + c]);
        }
        s_pa[tid] = rs;
    }
    __syncthreads();
    if (tid < M1) {
        const float rsum = s_pa[3 * tid] + s_pa[3 * tid + 1] + s_pa[3 * tid + 2];
        s_rowc[tid] = make_float2(__logf(rsum), 1.0f / rsum);
    }
    __syncthreads();

    // ---- pass 1b: col softmax denominators + col argmax (accuracy_next) ----
    if (act) {
        const int c = g;
        const float mcol = (c == MSZ) ? 0.0f : s_m1[c];
        float cs = 0.0f, best = -1.0f;
        int bidx = c0, tIdxn = 127;
        for (int i = 0; i < 27; ++i) {
            const int r = c0 + i;
            const float mn = mcol * s_m0[r];
            const float e = __expf(mn * s_x[r * M1 + c]);
            cs += e;
            if (e > best) { best = e; bidx = r; }     // first-max within chunk
            const float tn = tbitf(s_tb, r * M1 + c) * mn;
            if (tn != 0.0f && tIdxn == 127) tIdxn = r;
        }
        s_pa[tid] = cs;
        s_pv[tid] = best;
        s_pi[tid] = (unsigned char)bidx;
        s_pt[tid] = (unsigned char)tIdxn;
    }
    __syncthreads();
    if (tid < M1) {
        const int c = tid;
        const float csum = s_pa[3 * c] + s_pa[3 * c + 1] + s_pa[3 * c + 2];
        s_colc[c] = make_float4(s_m1[c], __logf(csum), 1.0f / csum, 0.0f);
        if (c < MSZ) {  // accuracy_next stats (cols < 80)
            float bv = s_pv[3 * c]; int bi = s_pi[3 * c];
            float v1 = s_pv[3 * c + 1]; if (v1 > bv) { bv = v1; bi = s_pi[3 * c + 1]; }
            float v2 = s_pv[3 * c + 2]; if (v2 > bv) { bv = v2; bi = s_pi[3 * c + 2]; }
            int ti = min(min((int)s_pt[3 * c], (int)s_pt[3 * c + 1]), (int)s_pt[3 * c + 2]);
            if (ti == 127) ti = 0;
            const float m1c = s_m1[c];
            a[9]  += (bi == ti) ? m1c : 0.0f;
            a[11] += m1c;
        }
    }
    __syncthreads();

    // ---- pass 2: all per-element sums + row argmax, 3 threads/row ----
    if (act) {
        const int r = g;
        const int rb = r * M1;
        const float m0f = s_m0[r];
        const float m0p = (r == MSZ) ? 0.0f : m0f;
        const float2 rc = s_rowc[r];
        const float lr = rc.x, invr = rc.y;
        float bbest = -3.402823466e38f;
        int bbidx = c0, tIdx = 127;
        const int cend = (j == 2) ? MSZ : (c0 + 27);
        for (int c = c0; c < cend; ++c) {
            const float4 cc = s_colc[c];
            const float m1c = cc.x, kc = cc.y, invc = cc.z;
            const float x = s_x[rb + c];
            const float t = tbitf(s_tb, rb + c);
            const float mf = m0f * m1c;       // mask_region (c<80 => == mnext)
            const float mp = m0p * m1c;       // mask_region_pre
            const float z = mf * x;           // valid arg wherever t-terms nonzero
            const float tp = t * mp;          // target_pre (== target_union, c<80)
            const float tn = t * mf;          // target_next
            a[0] += t;
            a[1] += tp;
            a[2] += tn;
            a[3] += tp;
            a[4] = fmaf(tp, lr - z, a[4]);    // -t*log(p_pre)
            a[5] = fmaf(tn, kc - z, a[5]);    // -t*log(p_next)
            const float mlk = fminf(lr, kc);
            a[6] = fmaf(tp, mlk - z, a[6]);   // -t*log(max(p_pre,p_next))
            const float e = __expf(z);
            a[7] = fmaf(tp * e, fabsf(invc - invr), a[7]);  // t*|p_next - p_pre|
            const float val = z - mlk;        // log input_all (monotone)
            if (val > bbest) { bbest = val; bbidx = c; }
            if (tp != 0.0f && tIdx == 127) tIdx = c;
        }
        if (j == 2) {  // peel c = 80: input_all = input_pre; no union/next terms
            const int c = MSZ;
            const float m1c = s_m1[c];
            const float x = s_x[rb + c];
            const float t = tbitf(s_tb, rb + c);
            const float mp = m0p * m1c;
            const float zp = mp * x;
            const float tp = t * mp;
            a[0] += t;
            a[1] += tp;
            a[4] = fmaf(tp, lr - zp, a[4]);
            a[6] = fmaf(tp, lr - zp, a[6]);
            const float val = zp - lr;
            if (val > bbest) { bbest = val; bbidx = c; }
            if (tp != 0.0f && tIdx == 127) tIdx = c;
        }
        s_pv[tid] = bbest;
        s_pi[tid] = (unsigned char)bbidx;
        s_pt[tid] = (unsigned char)tIdx;
    }
    __syncthreads();

    if (tid < MSZ) {  // merge row argmax (ascending chunks, strict >: first-max)
        const int r = tid;
        float bv = s_pv[3 * r]; int bi = s_pi[3 * r];
        float v1 = s_pv[3 * r + 1]; if (v1 > bv) { bv = v1; bi = s_pi[3 * r + 1]; }
        float v2 = s_pv[3 * r + 2]; if (v2 > bv) { bv = v2; bi = s_pi[3 * r + 2]; }
        int ti = min(min((int)s_pt[3 * r], (int)s_pt[3 * r + 1]), (int)s_pt[3 * r + 2]);
        if (ti == 127) ti = 0;
        out_idx[(size_t)slice * MSZ + r] = (float)bi;
        const float m0r = s_m0[r];
        a[8]  += (bi == ti) ? m0r : 0.0f;
        a[10] += m0r;
    }

    // ---- block reduce: wave shuffle -> LDS float atomic -> SoA partials ----
#pragma unroll
    for (int k = 0; k < NACC; ++k) {
        float v = a[k];
        for (int off = 32; off > 0; off >>= 1) v += __shfl_down(v, off);
        if ((tid & 63) == 0) atomicAdd(&s_accf[k], v);
    }
    __syncthreads();
    if (tid < NACC) part[(size_t)tid * slices + slice] = s_accf[tid];
}

__global__ __launch_bounds__(256) void sst_final(
    const float* __restrict__ part, int slices, float* __restrict__ out)
{
    __shared__ double s_part[4][NACC];
    const int tid = threadIdx.x;
    double l[NACC];
#pragma unroll
    for (int k = 0; k < NACC; ++k) l[k] = 0.0;
    for (int s = tid; s < slices; s += 256) {
#pragma unroll
        for (int k = 0; k < NACC; ++k) l[k] += (double)part[(size_t)k * slices + s];
    }
#pragma unroll
    for (int k = 0; k < NACC; ++k) {
        double v = l[k];
        for (int off = 32; off > 0; off >>= 1) v += __shfl_down(v, off);
        if ((tid & 63) == 0) s_part[tid >> 6][k] = v;
    }
    __syncthreads();
    if (tid == 0) {
        double g[NACC];
#pragma unroll
        for (int k = 0; k < NACC; ++k)
            g[k] = s_part[0][k] + s_part[1][k] + s_part[2][k] + s_part[3][k];
        const double tnum = g[0], npre = g[1], nnext = g[2], nunion = g[3];
        const double spre = g[4], snext = g[5], sall = g[6], ssim = g[7];
        const double accp = g[8], accn = g[9], nmp = g[10], nmn = g[11];
        const double loss_pre  = (npre > 0.0) ? spre / npre : spre;
        const double loss_next = (nnext > 0.0) ? snext / nnext : snext;
        const double loss      = (npre > 0.0 && nnext > 0.0) ? sall / npre : sall;
        const double loss_sim  = (nunion > 0.0) ? ssim / tnum : ssim;
        const double total = (loss_pre + loss_next + loss + loss_sim) * 0.25;
        const double ap = (nmp > 0.0) ? accp / nmp : accp + 1.0;
        const double an = (nmn > 0.0) ? accn / nmn : accn + 1.0;
        out[0] = (float)loss_pre;
        out[1] = (float)loss_next;
        out[2] = (float)loss_sim;
        out[3] = (float)total;
        out[4] = (float)ap;
        out[5] = (float)an;
        out[6] = (float)((ap + an) * 0.5);
    }
}

extern "C" void kernel_launch(void* const* d_in, const int* in_sizes, int n_in,
                              void* d_out, int out_size, void* d_ws, size_t ws_size,
                              hipStream_t stream) {
    const float* input  = (const float*)d_in[0];
    const int*   target = (const int*)d_in[1];
    const int*   mask0  = (const int*)d_in[2];
    const int*   mask1  = (const int*)d_in[3];
    float* out = (float*)d_out;
    float* part = (float*)d_ws;   // NACC * slices floats, SoA

    const int slices = in_sizes[0] / NEL;  // B*C = 2048

    sst_main<<<slices, 256, 0, stream>>>(input, target, mask0, mask1, out + 7, part, slices);
    sst_final<<<1, 256, 0, stream>>>(part, slices, out);
}